// Round 10
// baseline (427.945 us; speedup 1.0000x reference)
//
#include <hip/hip_runtime.h>

// Problem constants (from reference)
#define NB      128
#define ND      8
#define NK      8
#define TLEN    512
#define NSTEPS  496

__device__ __forceinline__ float fexp(float x) { return __expf(x); }
__device__ __forceinline__ float flog(float x) { return __logf(x); }
__device__ __forceinline__ float frcp(float x) { return __builtin_amdgcn_rcpf(x); }
__device__ __forceinline__ float elur(float x) { return x > 0.f ? x : fexp(x) - 1.f; }

// DPP helpers. Data replicated every 8 lanes => within a 16-lane row:
// quad_perm 0xB1 = lane^1, 0x4E = lane^2, row_ror:4 acts as lane^4.
#define DPP_QP0(v)  __int_as_float(__builtin_amdgcn_mov_dpp(__float_as_int(v), 0x00, 0xF, 0xF, false))
#define DPP_QP1(v)  __int_as_float(__builtin_amdgcn_mov_dpp(__float_as_int(v), 0x55, 0xF, 0xF, false))
#define DPP_QP2(v)  __int_as_float(__builtin_amdgcn_mov_dpp(__float_as_int(v), 0xAA, 0xF, 0xF, false))
#define DPP_QP3(v)  __int_as_float(__builtin_amdgcn_mov_dpp(__float_as_int(v), 0xFF, 0xF, 0xF, false))
#define DPP_ROR4(v) __int_as_float(__builtin_amdgcn_mov_dpp(__float_as_int(v), 0x124, 0xF, 0xF, false))
#define DPP_X1(v)   __int_as_float(__builtin_amdgcn_mov_dpp(__float_as_int(v), 0xB1, 0xF, 0xF, false))
#define DPP_X2(v)   __int_as_float(__builtin_amdgcn_mov_dpp(__float_as_int(v), 0x4E, 0xF, 0xF, false))

#define RED8_MAX(m) { m = fmaxf(m, DPP_X1(m)); m = fmaxf(m, DPP_X2(m)); m = fmaxf(m, DPP_ROR4(m)); }
#define RED8_SUM(s) { s = s + DPP_X1(s); s = s + DPP_X2(s); s = s + DPP_ROR4(s); }

// v + v[lane^32] on all lanes, via VALU permlane32_swap (no DS pipe).
#if defined(__has_builtin)
#if __has_builtin(__builtin_amdgcn_permlane32_swap)
#define HAVE_PLSWAP 1
#endif
#endif
#ifdef HAVE_PLSWAP
typedef unsigned int uint2v __attribute__((ext_vector_type(2)));
__device__ __forceinline__ float xhalfsum(float v) {
    unsigned int u = __float_as_uint(v);
    uint2v r = __builtin_amdgcn_permlane32_swap(u, u, false, false);
    return __uint_as_float(r[0]) + __uint_as_float(r[1]);
}
#else
__device__ __forceinline__ float xhalfsum(float v) { return v + __shfl_xor(v, 32); }
#endif

// 16-term dot over LDS (4x b128)
__device__ __forceinline__ float ldot16(const float* p, const float* w) {
    const float4* q4 = (const float4*)p;
    float a0 = 0.f, a1 = 0.f, a2 = 0.f, a3 = 0.f;
    #pragma unroll
    for (int i = 0; i < 4; ++i) {
        float4 v = q4[i];
        a0 = fmaf(w[4*i+0], v.x, a0);
        a1 = fmaf(w[4*i+1], v.y, a1);
        a2 = fmaf(w[4*i+2], v.z, a2);
        a3 = fmaf(w[4*i+3], v.w, a3);
    }
    return (a0 + a1) + (a2 + a3);
}

__device__ __forceinline__ float ldot8(const float* p, const float* w) {
    const float4* q4 = (const float4*)p;
    float4 a = q4[0], b = q4[1];
    float s0 = fmaf(w[0], a.x, fmaf(w[1], a.y, 0.f));
    float s1 = fmaf(w[2], a.z, fmaf(w[3], a.w, 0.f));
    float s2 = fmaf(w[4], b.x, fmaf(w[5], b.y, 0.f));
    float s3 = fmaf(w[6], b.z, fmaf(w[7], b.w, 0.f));
    return (s0 + s1) + (s2 + s3);
}

// One scan step. Lanes = 32 channels x 2 K-halves. ZP = F(q-2) slots (overwritten
// with F(q)), RP its 1/sum; ZC = F(q-1), RC its 1/sum (y = F*R).
// Slot k holds channel k^4p, p = (lane>>2)&1. Old-tap dots issued in the shadow
// of the next layer's LDS reads. ZQ2 at tail == wzo.y(q-1).
#define STEP(qv, S1, S2, S3, ZP, ZC, RP, RC, DO_OUT)                              \
  {                                                                               \
    const int q_ = (qv);                                                          \
    float g_own = 0.f;                                                            \
    if (DO_OUT) g_own = gls[(q_ - 15) * NK + o3];  /* hoisted */                  \
    /* layer 0: dz = (sum wzn.ZC) * RC  (old tap folded into XZ) */               \
    float _z0 = fmaf(wzn[0], ZC[0], 0.f);                                         \
    float _z1 = fmaf(wzn[1], ZC[1], 0.f);                                         \
    float _z2 = fmaf(wzn[2], ZC[2], 0.f);                                         \
    float _z3 = fmaf(wzn[3], ZC[3], 0.f);                                         \
    _z0 = fmaf(wzn[4], ZC[4], _z0);                                               \
    _z1 = fmaf(wzn[5], ZC[5], _z1);                                               \
    _z2 = fmaf(wzn[6], ZC[6], _z2);                                               \
    _z3 = fmaf(wzn[7], ZC[7], _z3);                                               \
    float o0v = elur(XZ + ((_z0 + _z1) + (_z2 + _z3)) * RC);                      \
    bc0[lane] = o0v;                                                              \
    /* layer 1 */                                                                 \
    float n1 = ldot16(bc0 + hoff, w1n);                                           \
    float o1v = elur(xhalfsum(n1) + P1[S1]);                                      \
    bc1[lane] = o1v;                                                              \
    float d1o = ldot16(bc0 + hoff, w1o);   /* in shadow of layer-2 reads */       \
    P1[S1] = b1r + xhalfsum(d1o);                                                 \
    /* layer 2 */                                                                 \
    float n2 = ldot16(bc1 + hoff, w2n);                                           \
    float o2v = elur(xhalfsum(n2) + P2[S2]);                                      \
    bc2[lane] = o2v;                                                              \
    float d2o = ldot16(bc1 + hoff, w2o);                                          \
    P2[S2] = b2r + xhalfsum(d2o);                                                 \
    /* layer 3 */                                                                 \
    float n3 = ldot16(bc2 + hoff, w3n);                                           \
    float a3m = elur(xhalfsum(n3) + P3[S3]);                                      \
    if (DO_OUT) {                                                                 \
      /* gumbel-softmax on critical path: single exp + DPP reduce/broadcast */    \
      float T = (a3m + g_own) * tinv;                                             \
      float m2 = T; RED8_MAX(m2);                                                 \
      float F = fexp(T - m2);                                                     \
      float S = F; RED8_SUM(S);                                                   \
      float r2 = frcp(S);                                                         \
      RP = r2;                                                                    \
      float _t = DPP_ROR4(F);                                                     \
      ZP[0] = DPP_QP0(F);  ZP[1] = DPP_QP1(F);  ZP[2] = DPP_QP2(F);               \
      ZP[3] = DPP_QP3(F);                                                         \
      ZP[4] = DPP_QP0(_t); ZP[5] = DPP_QP1(_t); ZP[6] = DPP_QP2(_t);              \
      ZP[7] = DPP_QP3(_t);                                                        \
      /* off-path: layer-3 old-tap park */                                        \
      float d3o = ldot16(bc2 + hoff, w3o);                                        \
      P3[S3] = b3r + xhalfsum(d3o);                                               \
      /* off-path: old-tap z-dot wzo.y(q_) — consumed at step q_+2 */             \
      {                                                                           \
        float z0 = fmaf(wzo[0], ZP[0], fmaf(wzo[1], ZP[1], 0.f));                 \
        float z1 = fmaf(wzo[2], ZP[2], fmaf(wzo[3], ZP[3], 0.f));                 \
        float z2 = fmaf(wzo[4], ZP[4], fmaf(wzo[5], ZP[5], 0.f));                 \
        float z3 = fmaf(wzo[6], ZP[6], fmaf(wzo[7], ZP[7], 0.f));                 \
        ZQ2n = ((z0 + z1) + (z2 + z3)) * r2;                                      \
      }                                                                           \
      /* off-path: log-softmax output */                                          \
      float mx = a3m; RED8_MAX(mx);                                               \
      float e = fexp(a3m - mx);                                                   \
      float se = e; RED8_SUM(se);                                                 \
      float lse = mx + flog(se);                                                  \
      if (lane < 8) {                                                             \
        outg[zoff + lane * TLEN + q_ + 1]       = F * r2;                         \
        outg[qoff + lane * NSTEPS + (q_ - 15)]  = a3m - lse;                      \
      }                                                                           \
    } else {                                                                      \
      float d3o = ldot16(bc2 + hoff, w3o);                                        \
      P3[S3] = b3r + xhalfsum(d3o);                                               \
    }                                                                             \
    /* park x-part + old-z for step q_+1: ZQ2 == wzo.y(q_-1) here */              \
    {                                                                             \
      float xp = ldot8(&xcol[q_ + tap][0], wxr);                                  \
      XZ = xhalfsum(xp) + b0r + ZQ2;                                              \
      ZQ2 = ZQ2n;                                                                 \
    }                                                                             \
  }

__global__ __launch_bounds__(64, 1)
void regime_scan_kernel(const float* __restrict__ xg,
                        const float* __restrict__ tempg,
                        const float* __restrict__ ug,
                        const float* __restrict__ w0g,
                        const float* __restrict__ b0g,
                        const float* __restrict__ w1g,
                        const float* __restrict__ b1g,
                        const float* __restrict__ w2g,
                        const float* __restrict__ b2g,
                        const float* __restrict__ w3g,
                        const float* __restrict__ b3g,
                        float* __restrict__ outg)
{
    __shared__ __align__(16) float xcol[527][8];     // 16.9 KB
    __shared__ __align__(16) float gls[NSTEPS * NK]; // 15.9 KB
    __shared__ __align__(16) float bc0[64], bc1[64], bc2[64];

    const int lane = threadIdx.x;
    const int b    = blockIdx.x;
    const int c    = lane & 31;            // channel owned
    const int o3   = lane & 7;             // layer-3 channel owned
    const int half = lane >> 5;            // K-half owned (layers 1-3)
    const int hoff = half << 4;            // float offset into bc
    const int tap  = (lane < 32) ? 1 : 0;  // x-park tap role
    const int p4   = (lane & 4);           // slot-order parity*4

    // ---- per-lane weights ----
    float wzn[8], wzo[8];                  // layer0 z weights, slot order
    #pragma unroll
    for (int k = 0; k < 8; ++k) {
        int ch = k ^ p4;
        wzn[k] = w0g[c * 32 + (8 + ch) * 2 + 1];
        wzo[k] = w0g[c * 32 + (8 + ch) * 2 + 0];
    }
    float wxr[8];
    #pragma unroll
    for (int d = 0; d < 8; ++d) wxr[d] = w0g[c * 32 + d * 2 + tap];
    float w1n[16], w1o[16], w2n[16], w2o[16], w3n[16], w3o[16];
    #pragma unroll
    for (int i = 0; i < 16; ++i) {
        int j = hoff + i;
        w1n[i] = w1g[c * 64 + j * 2 + 1];
        w1o[i] = w1g[c * 64 + j * 2 + 0];
        w2n[i] = w2g[c * 64 + j * 2 + 1];
        w2o[i] = w2g[c * 64 + j * 2 + 0];
        w3n[i] = w3g[o3 * 64 + j * 2 + 1];
        w3o[i] = w3g[o3 * 64 + j * 2 + 0];
    }
    const float b0r  = b0g[c];
    const float b1r  = b1g[c];
    const float b2r  = b2g[c];
    const float b3r  = b3g[o3];
    const float tinv = frcp(tempg[0]);

    // ---- prologue: x columns ----
    if (lane < 15) {
        #pragma unroll
        for (int d = 0; d < ND; ++d) xcol[lane][d] = 0.f;
    }
    const float* xb = xg + b * (ND * TLEN);
    for (int t = lane; t < TLEN; t += 64) {
        #pragma unroll
        for (int d = 0; d < ND; ++d) xcol[15 + t][d] = xb[d * TLEN + t];
    }
    // ---- prologue: Gumbel noise ----
    for (int idx = lane; idx < NSTEPS * NK; idx += 64) {
        int s = idx >> 3, k = idx & 7;
        float uu = ug[s * (NB * NK) + b * NK + k];
        gls[idx] = -flog(-flog(uu + 1e-10f) + 1e-10f);
    }
    // ---- z_all[:, :, 0:16] = 0 ----
    const int zoff = b * (NK * TLEN);
    const int qoff = NB * NK * TLEN + b * (NK * NSTEPS);
    for (int idx = lane; idx < NK * 16; idx += 64) {
        outg[zoff + (idx >> 4) * TLEN + (idx & 15)] = 0.f;
    }

    // ---- state ----
    float zA[8], zB[8];
    #pragma unroll
    for (int k = 0; k < 8; ++k) { zA[k] = 0.f; zB[k] = 0.f; }
    float RA = 1.f, RB = 1.f;              // 1/sum for each z buffer
    float P1[2] = { b1r, b1r };
    float P2[4] = { b2r, b2r, b2r, b2r };
    float P3[8];
    #pragma unroll
    for (int k = 0; k < 8; ++k) P3[k] = b3r;
    float ZQ2 = 0.f, ZQ2n = 0.f;
    float XZ;
    {
        float xp = ldot8(&xcol[tap][0], wxr);
        XZ = xhalfsum(xp) + b0r;   // old-tap z = 0
    }

    // ---- warmup q=1..14 ----
    #pragma unroll
    for (int q = 1; q <= 14; ++q) STEP(q, q & 1, q & 3, q & 7, zA, zB, RA, RB, 0);

    // ---- main loop q=15..510, unrolled by 8; z double-buffer by parity ----
    for (int qb = 15; qb <= 503; qb += 8) {
        #pragma unroll
        for (int u = 0; u < 8; u += 2) {
            STEP(qb + u,     (15 + u) & 1, (15 + u) & 3, (15 + u) & 7, zA, zB, RA, RB, 1);
            STEP(qb + u + 1, (16 + u) & 1, (16 + u) & 3, (16 + u) & 7, zB, zA, RB, RA, 1);
        }
    }
}

extern "C" void kernel_launch(void* const* d_in, const int* in_sizes, int n_in,
                              void* d_out, int out_size, void* d_ws, size_t ws_size,
                              hipStream_t stream) {
    (void)in_sizes; (void)n_in; (void)out_size; (void)d_ws; (void)ws_size;
    regime_scan_kernel<<<dim3(NB), dim3(64), 0, stream>>>(
        (const float*)d_in[0],   // x
        (const float*)d_in[1],   // temp
        (const float*)d_in[2],   // u
        (const float*)d_in[3],   // w0
        (const float*)d_in[4],   // b0
        (const float*)d_in[5],   // w1
        (const float*)d_in[6],   // b1
        (const float*)d_in[7],   // w2
        (const float*)d_in[8],   // b2
        (const float*)d_in[9],   // w3
        (const float*)d_in[10],  // b3
        (float*)d_out);
}

// Round 11
// 374.538 us; speedup vs baseline: 1.1426x; 1.1426x over previous
//
#include <hip/hip_runtime.h>

// Problem constants (from reference)
#define NB      128
#define ND      8
#define NK      8
#define TLEN    512
#define NSTEPS  496

__device__ __forceinline__ float fexp(float x) { return __expf(x); }
__device__ __forceinline__ float flog(float x) { return __logf(x); }
__device__ __forceinline__ float frcp(float x) { return __builtin_amdgcn_rcpf(x); }
__device__ __forceinline__ float elur(float x) { return x > 0.f ? x : fexp(x) - 1.f; }

// DPP helpers. Data replicated every 8 lanes => within a 16-lane row:
// quad_perm 0xB1 = lane^1, 0x4E = lane^2, row_ror:4 acts as lane^4.
#define DPP_QP0(v)  __int_as_float(__builtin_amdgcn_mov_dpp(__float_as_int(v), 0x00, 0xF, 0xF, false))
#define DPP_QP1(v)  __int_as_float(__builtin_amdgcn_mov_dpp(__float_as_int(v), 0x55, 0xF, 0xF, false))
#define DPP_QP2(v)  __int_as_float(__builtin_amdgcn_mov_dpp(__float_as_int(v), 0xAA, 0xF, 0xF, false))
#define DPP_QP3(v)  __int_as_float(__builtin_amdgcn_mov_dpp(__float_as_int(v), 0xFF, 0xF, 0xF, false))
#define DPP_ROR4(v) __int_as_float(__builtin_amdgcn_mov_dpp(__float_as_int(v), 0x124, 0xF, 0xF, false))
#define DPP_X1(v)   __int_as_float(__builtin_amdgcn_mov_dpp(__float_as_int(v), 0xB1, 0xF, 0xF, false))
#define DPP_X2(v)   __int_as_float(__builtin_amdgcn_mov_dpp(__float_as_int(v), 0x4E, 0xF, 0xF, false))

#define RED8_MAX(m) { m = fmaxf(m, DPP_X1(m)); m = fmaxf(m, DPP_X2(m)); m = fmaxf(m, DPP_ROR4(m)); }
#define RED8_SUM(s) { s = s + DPP_X1(s); s = s + DPP_X2(s); s = s + DPP_ROR4(s); }

// v + v[lane^32] on all lanes, via VALU permlane32_swap (no DS pipe).
#if defined(__has_builtin)
#if __has_builtin(__builtin_amdgcn_permlane32_swap)
#define HAVE_PLSWAP 1
#endif
#endif
#ifdef HAVE_PLSWAP
typedef unsigned int uint2v __attribute__((ext_vector_type(2)));
__device__ __forceinline__ float xhalfsum(float v) {
    unsigned int u = __float_as_uint(v);
    uint2v r = __builtin_amdgcn_permlane32_swap(u, u, false, false);
    return __uint_as_float(r[0]) + __uint_as_float(r[1]);
}
#else
__device__ __forceinline__ float xhalfsum(float v) { return v + __shfl_xor(v, 32); }
#endif

// dual 16-term dot (new+old tap weights) over 16 floats of LDS (4x b128 reads,
// both dots reuse the same loaded registers — do NOT split, compiler won't CSE)
__device__ __forceinline__ void ldot16x2(const float* p, const float* wn, const float* wo,
                                         float& dn, float& dd) {
    const float4* q4 = (const float4*)p;
    float n0 = 0.f, n1 = 0.f, o0 = 0.f, o1 = 0.f;
    #pragma unroll
    for (int i = 0; i < 4; ++i) {
        float4 v = q4[i];
        n0 = fmaf(wn[4*i+0], v.x, n0);
        n1 = fmaf(wn[4*i+1], v.y, n1);
        o0 = fmaf(wo[4*i+0], v.x, o0);
        o1 = fmaf(wo[4*i+1], v.y, o1);
        n0 = fmaf(wn[4*i+2], v.z, n0);
        n1 = fmaf(wn[4*i+3], v.w, n1);
        o0 = fmaf(wo[4*i+2], v.z, o0);
        o1 = fmaf(wo[4*i+3], v.w, o1);
    }
    dn = n0 + n1;
    dd = o0 + o1;
}

// One scan step. Lanes = 32 channels x 2 K-halves. ZP = F(q-2) slots (overwritten
// with F(q)), RP its 1/sum; ZC = F(q-1), RC its 1/sum (y = F*R).
// Slot k holds channel k^4p, p = (lane>>2)&1. ZQ2 at tail == wzo.y(q-1).
#define STEP(qv, S1, S2, S3, ZP, ZC, RP, RC, DO_OUT)                              \
  {                                                                               \
    const int q_ = (qv);                                                          \
    /* preload step-local LDS data (no recurrence dep — latency hidden) */        \
    float g_own = 0.f;                                                            \
    if (DO_OUT) g_own = gls[(q_ - 15) * NK + o3];                                 \
    const float4* _xq = (const float4*)&xcol[q_ + tap][0];                        \
    float4 _xa = _xq[0], _xb = _xq[1];                                            \
    /* layer 0: dz = (sum wzn.ZC) * RC  (old tap folded into XZ) */               \
    float _z0 = fmaf(wzn[0], ZC[0], 0.f);                                         \
    float _z1 = fmaf(wzn[1], ZC[1], 0.f);                                         \
    float _z2 = fmaf(wzn[2], ZC[2], 0.f);                                         \
    float _z3 = fmaf(wzn[3], ZC[3], 0.f);                                         \
    _z0 = fmaf(wzn[4], ZC[4], _z0);                                               \
    _z1 = fmaf(wzn[5], ZC[5], _z1);                                               \
    _z2 = fmaf(wzn[6], ZC[6], _z2);                                               \
    _z3 = fmaf(wzn[7], ZC[7], _z3);                                               \
    float o0v = elur(XZ + ((_z0 + _z1) + (_z2 + _z3)) * RC);                      \
    bc0[lane] = o0v;                                                              \
    /* layer 1 */                                                                 \
    float n1, d1o;                                                                \
    ldot16x2(bc0 + hoff, w1n, w1o, n1, d1o);                                      \
    float o1v = elur(xhalfsum(n1) + P1[S1]);                                      \
    bc1[lane] = o1v;                                                              \
    P1[S1] = b1r + xhalfsum(d1o);                                                 \
    /* layer 2 */                                                                 \
    float n2, d2o;                                                                \
    ldot16x2(bc1 + hoff, w2n, w2o, n2, d2o);                                      \
    float o2v = elur(xhalfsum(n2) + P2[S2]);                                      \
    bc2[lane] = o2v;                                                              \
    P2[S2] = b2r + xhalfsum(d2o);                                                 \
    /* layer 3 */                                                                 \
    float n3, d3o;                                                                \
    ldot16x2(bc2 + hoff, w3n, w3o, n3, d3o);                                      \
    float a3m = elur(xhalfsum(n3) + P3[S3]);                                      \
    P3[S3] = b3r + xhalfsum(d3o);                                                 \
    if (DO_OUT) {                                                                 \
      /* gumbel-softmax on critical path: single exp + DPP reduce/broadcast */    \
      float T = (a3m + g_own) * tinv;                                             \
      float m2 = T; RED8_MAX(m2);                                                 \
      float F = fexp(T - m2);                                                     \
      float S = F; RED8_SUM(S);                                                   \
      float r2 = frcp(S);                                                         \
      RP = r2;                                                                    \
      float _t = DPP_ROR4(F);                                                     \
      ZP[0] = DPP_QP0(F);  ZP[1] = DPP_QP1(F);  ZP[2] = DPP_QP2(F);               \
      ZP[3] = DPP_QP3(F);                                                         \
      ZP[4] = DPP_QP0(_t); ZP[5] = DPP_QP1(_t); ZP[6] = DPP_QP2(_t);              \
      ZP[7] = DPP_QP3(_t);                                                        \
      /* off-path: old-tap z-dot wzo.y(q_) — consumed at step q_+2 */             \
      {                                                                           \
        float z0 = fmaf(wzo[0], ZP[0], fmaf(wzo[1], ZP[1], 0.f));                 \
        float z1 = fmaf(wzo[2], ZP[2], fmaf(wzo[3], ZP[3], 0.f));                 \
        float z2 = fmaf(wzo[4], ZP[4], fmaf(wzo[5], ZP[5], 0.f));                 \
        float z3 = fmaf(wzo[6], ZP[6], fmaf(wzo[7], ZP[7], 0.f));                 \
        ZQ2n = ((z0 + z1) + (z2 + z3)) * r2;                                      \
      }                                                                           \
      /* off-path: log-softmax output */                                          \
      float mx = a3m; RED8_MAX(mx);                                               \
      float e = fexp(a3m - mx);                                                   \
      float se = e; RED8_SUM(se);                                                 \
      float lse = mx + flog(se);                                                  \
      if (lane < 8) {                                                             \
        outg[zoff + lane * TLEN + q_ + 1]       = F * r2;                         \
        outg[qoff + lane * NSTEPS + (q_ - 15)]  = a3m - lse;                      \
      }                                                                           \
    }                                                                             \
    /* park x-part + old-z for step q_+1 (xcol data preloaded at step start) */   \
    {                                                                             \
      float s0 = fmaf(wxr[0], _xa.x, fmaf(wxr[1], _xa.y, 0.f));                   \
      float s1 = fmaf(wxr[2], _xa.z, fmaf(wxr[3], _xa.w, 0.f));                   \
      float s2 = fmaf(wxr[4], _xb.x, fmaf(wxr[5], _xb.y, 0.f));                   \
      float s3 = fmaf(wxr[6], _xb.z, fmaf(wxr[7], _xb.w, 0.f));                   \
      float xp = (s0 + s1) + (s2 + s3);                                           \
      XZ = xhalfsum(xp) + b0r + ZQ2;                                              \
      ZQ2 = ZQ2n;                                                                 \
    }                                                                             \
  }

__global__ __launch_bounds__(64, 1)
void regime_scan_kernel(const float* __restrict__ xg,
                        const float* __restrict__ tempg,
                        const float* __restrict__ ug,
                        const float* __restrict__ w0g,
                        const float* __restrict__ b0g,
                        const float* __restrict__ w1g,
                        const float* __restrict__ b1g,
                        const float* __restrict__ w2g,
                        const float* __restrict__ b2g,
                        const float* __restrict__ w3g,
                        const float* __restrict__ b3g,
                        float* __restrict__ outg)
{
    __shared__ __align__(16) float xcol[527][8];     // 16.9 KB
    __shared__ __align__(16) float gls[NSTEPS * NK]; // 15.9 KB
    __shared__ __align__(16) float bc0[64], bc1[64], bc2[64];

    const int lane = threadIdx.x;
    const int b    = blockIdx.x;
    const int c    = lane & 31;            // channel owned
    const int o3   = lane & 7;             // layer-3 channel owned
    const int half = lane >> 5;            // K-half owned (layers 1-3)
    const int hoff = half << 4;            // float offset into bc
    const int tap  = (lane < 32) ? 1 : 0;  // x-park tap role
    const int p4   = (lane & 4);           // slot-order parity*4

    // ---- per-lane weights ----
    float wzn[8], wzo[8];                  // layer0 z weights, slot order
    #pragma unroll
    for (int k = 0; k < 8; ++k) {
        int ch = k ^ p4;
        wzn[k] = w0g[c * 32 + (8 + ch) * 2 + 1];
        wzo[k] = w0g[c * 32 + (8 + ch) * 2 + 0];
    }
    float wxr[8];
    #pragma unroll
    for (int d = 0; d < 8; ++d) wxr[d] = w0g[c * 32 + d * 2 + tap];
    float w1n[16], w1o[16], w2n[16], w2o[16], w3n[16], w3o[16];
    #pragma unroll
    for (int i = 0; i < 16; ++i) {
        int j = hoff + i;
        w1n[i] = w1g[c * 64 + j * 2 + 1];
        w1o[i] = w1g[c * 64 + j * 2 + 0];
        w2n[i] = w2g[c * 64 + j * 2 + 1];
        w2o[i] = w2g[c * 64 + j * 2 + 0];
        w3n[i] = w3g[o3 * 64 + j * 2 + 1];
        w3o[i] = w3g[o3 * 64 + j * 2 + 0];
    }
    const float b0r  = b0g[c];
    const float b1r  = b1g[c];
    const float b2r  = b2g[c];
    const float b3r  = b3g[o3];
    const float tinv = frcp(tempg[0]);

    // ---- prologue: x columns ----
    if (lane < 15) {
        #pragma unroll
        for (int d = 0; d < ND; ++d) xcol[lane][d] = 0.f;
    }
    const float* xb = xg + b * (ND * TLEN);
    for (int t = lane; t < TLEN; t += 64) {
        #pragma unroll
        for (int d = 0; d < ND; ++d) xcol[15 + t][d] = xb[d * TLEN + t];
    }
    // ---- prologue: Gumbel noise ----
    for (int idx = lane; idx < NSTEPS * NK; idx += 64) {
        int s = idx >> 3, k = idx & 7;
        float uu = ug[s * (NB * NK) + b * NK + k];
        gls[idx] = -flog(-flog(uu + 1e-10f) + 1e-10f);
    }
    // ---- z_all[:, :, 0:16] = 0 ----
    const int zoff = b * (NK * TLEN);
    const int qoff = NB * NK * TLEN + b * (NK * NSTEPS);
    for (int idx = lane; idx < NK * 16; idx += 64) {
        outg[zoff + (idx >> 4) * TLEN + (idx & 15)] = 0.f;
    }

    // ---- state ----
    float zA[8], zB[8];
    #pragma unroll
    for (int k = 0; k < 8; ++k) { zA[k] = 0.f; zB[k] = 0.f; }
    float RA = 1.f, RB = 1.f;              // 1/sum for each z buffer
    float P1[2] = { b1r, b1r };
    float P2[4] = { b2r, b2r, b2r, b2r };
    float P3[8];
    #pragma unroll
    for (int k = 0; k < 8; ++k) P3[k] = b3r;
    float ZQ2 = 0.f, ZQ2n = 0.f;
    float XZ;
    {
        const float4* xq = (const float4*)&xcol[tap][0];
        float4 xa = xq[0], xbv = xq[1];
        float s0 = fmaf(wxr[0], xa.x, fmaf(wxr[1], xa.y, 0.f));
        float s1 = fmaf(wxr[2], xa.z, fmaf(wxr[3], xa.w, 0.f));
        float s2 = fmaf(wxr[4], xbv.x, fmaf(wxr[5], xbv.y, 0.f));
        float s3 = fmaf(wxr[6], xbv.z, fmaf(wxr[7], xbv.w, 0.f));
        XZ = xhalfsum((s0 + s1) + (s2 + s3)) + b0r;   // old-tap z = 0
    }

    // ---- warmup q=1..14 ----
    #pragma unroll
    for (int q = 1; q <= 14; ++q) STEP(q, q & 1, q & 3, q & 7, zA, zB, RA, RB, 0);

    // ---- main loop q=15..510, unrolled by 8; z double-buffer by parity ----
    for (int qb = 15; qb <= 503; qb += 8) {
        #pragma unroll
        for (int u = 0; u < 8; u += 2) {
            STEP(qb + u,     (15 + u) & 1, (15 + u) & 3, (15 + u) & 7, zA, zB, RA, RB, 1);
            STEP(qb + u + 1, (16 + u) & 1, (16 + u) & 3, (16 + u) & 7, zB, zA, RB, RA, 1);
        }
    }
}

extern "C" void kernel_launch(void* const* d_in, const int* in_sizes, int n_in,
                              void* d_out, int out_size, void* d_ws, size_t ws_size,
                              hipStream_t stream) {
    (void)in_sizes; (void)n_in; (void)out_size; (void)d_ws; (void)ws_size;
    regime_scan_kernel<<<dim3(NB), dim3(64), 0, stream>>>(
        (const float*)d_in[0],   // x
        (const float*)d_in[1],   // temp
        (const float*)d_in[2],   // u
        (const float*)d_in[3],   // w0
        (const float*)d_in[4],   // b0
        (const float*)d_in[5],   // w1
        (const float*)d_in[6],   // b1
        (const float*)d_in[7],   // w2
        (const float*)d_in[8],   // b2
        (const float*)d_in[9],   // w3
        (const float*)d_in[10],  // b3
        (float*)d_out);
}

// Round 12
// 364.059 us; speedup vs baseline: 1.1755x; 1.0288x over previous
//
#include <hip/hip_runtime.h>

// Problem constants (from reference)
#define NB      128
#define ND      8
#define NK      8
#define TLEN    512
#define NSTEPS  496

#define INVLN2f 1.44269504088896340736f

__device__ __forceinline__ float fexp(float x) { return __expf(x); }
__device__ __forceinline__ float flog(float x) { return __logf(x); }
__device__ __forceinline__ float frcp(float x) { return __builtin_amdgcn_rcpf(x); }
__device__ __forceinline__ float elur(float x) { return x > 0.f ? x : fexp(x) - 1.f; }

#if defined(__has_builtin)
#if __has_builtin(__builtin_amdgcn_exp2f)
#define fexp2(x) __builtin_amdgcn_exp2f(x)
#endif
#endif
#ifndef fexp2
#define fexp2(x) exp2f(x)
#endif

// DPP helpers. Data replicated every 8 lanes => within a 16-lane row:
// quad_perm 0xB1 = lane^1, 0x4E = lane^2, row_ror:4 acts as lane^4.
#define DPP_QP0(v)  __int_as_float(__builtin_amdgcn_mov_dpp(__float_as_int(v), 0x00, 0xF, 0xF, false))
#define DPP_QP1(v)  __int_as_float(__builtin_amdgcn_mov_dpp(__float_as_int(v), 0x55, 0xF, 0xF, false))
#define DPP_QP2(v)  __int_as_float(__builtin_amdgcn_mov_dpp(__float_as_int(v), 0xAA, 0xF, 0xF, false))
#define DPP_QP3(v)  __int_as_float(__builtin_amdgcn_mov_dpp(__float_as_int(v), 0xFF, 0xF, 0xF, false))
#define DPP_ROR4(v) __int_as_float(__builtin_amdgcn_mov_dpp(__float_as_int(v), 0x124, 0xF, 0xF, false))
#define DPP_X1(v)   __int_as_float(__builtin_amdgcn_mov_dpp(__float_as_int(v), 0xB1, 0xF, 0xF, false))
#define DPP_X2(v)   __int_as_float(__builtin_amdgcn_mov_dpp(__float_as_int(v), 0x4E, 0xF, 0xF, false))

#define RED8_MAX(m) { m = fmaxf(m, DPP_X1(m)); m = fmaxf(m, DPP_X2(m)); m = fmaxf(m, DPP_ROR4(m)); }
#define RED8_SUM(s) { s = s + DPP_X1(s); s = s + DPP_X2(s); s = s + DPP_ROR4(s); }

// v + v[lane^32] on all lanes, via VALU permlane32_swap (no DS pipe).
#if defined(__has_builtin)
#if __has_builtin(__builtin_amdgcn_permlane32_swap)
#define HAVE_PLSWAP 1
#endif
#endif
#ifdef HAVE_PLSWAP
typedef unsigned int uint2v __attribute__((ext_vector_type(2)));
__device__ __forceinline__ float xhalfsum(float v) {
    unsigned int u = __float_as_uint(v);
    uint2v r = __builtin_amdgcn_permlane32_swap(u, u, false, false);
    return __uint_as_float(r[0]) + __uint_as_float(r[1]);
}
#else
__device__ __forceinline__ float xhalfsum(float v) { return v + __shfl_xor(v, 32); }
#endif

// dual 16-term dot (new+old tap weights) over 16 floats of LDS (4x b128 reads,
// both dots reuse the same loaded registers — do NOT split, compiler won't CSE)
__device__ __forceinline__ void ldot16x2(const float* p, const float* wn, const float* wo,
                                         float& dn, float& dd) {
    const float4* q4 = (const float4*)p;
    float n0 = 0.f, n1 = 0.f, o0 = 0.f, o1 = 0.f;
    #pragma unroll
    for (int i = 0; i < 4; ++i) {
        float4 v = q4[i];
        n0 = fmaf(wn[4*i+0], v.x, n0);
        n1 = fmaf(wn[4*i+1], v.y, n1);
        o0 = fmaf(wo[4*i+0], v.x, o0);
        o1 = fmaf(wo[4*i+1], v.y, o1);
        n0 = fmaf(wn[4*i+2], v.z, n0);
        n1 = fmaf(wn[4*i+3], v.w, n1);
        o0 = fmaf(wo[4*i+2], v.z, o0);
        o1 = fmaf(wo[4*i+3], v.w, o1);
    }
    dn = n0 + n1;
    dd = o0 + o1;
}

// One scan step. Lanes = 32 channels x 2 K-halves. ZP = F(q-2) slots (overwritten
// with F(q)), RP its 1/sum; ZC = F(q-1), RC its 1/sum (y = F*R).
// Slot k holds channel k^4p, p = (lane>>2)&1. ZQ2 at tail == wzo.y(q-1).
// gls holds g2 = gumbel * tinv * 1/ln2; F = 2^(a3*klog + g2) (max-sub skipped:
// shift-invariant, inputs bounded -> no overflow; temp == 1 per setup).
#define STEP(qv, S1, S2, S3, ZP, ZC, RP, RC, DO_OUT)                              \
  {                                                                               \
    const int q_ = (qv);                                                          \
    /* preload step-local LDS data (no recurrence dep — latency hidden) */        \
    float g2_own = 0.f;                                                           \
    if (DO_OUT) g2_own = gls[(q_ - 15) * NK + o3];                                \
    const float4* _xq = (const float4*)&xcol[q_ + tap][0];                        \
    float4 _xa = _xq[0], _xb = _xq[1];                                            \
    /* layer 0: o0 = elur(fma(dz, RC, XZ))  (old tap folded into XZ) */           \
    float _z0 = fmaf(wzn[0], ZC[0], 0.f);                                         \
    float _z1 = fmaf(wzn[1], ZC[1], 0.f);                                         \
    float _z2 = fmaf(wzn[2], ZC[2], 0.f);                                         \
    float _z3 = fmaf(wzn[3], ZC[3], 0.f);                                         \
    _z0 = fmaf(wzn[4], ZC[4], _z0);                                               \
    _z1 = fmaf(wzn[5], ZC[5], _z1);                                               \
    _z2 = fmaf(wzn[6], ZC[6], _z2);                                               \
    _z3 = fmaf(wzn[7], ZC[7], _z3);                                               \
    float o0v = elur(fmaf((_z0 + _z1) + (_z2 + _z3), RC, XZ));                    \
    bc0[lane] = o0v;                                                              \
    /* layer 1 */                                                                 \
    float n1, d1o;                                                                \
    ldot16x2(bc0 + hoff, w1n, w1o, n1, d1o);                                      \
    float o1v = elur(xhalfsum(n1) + P1[S1]);                                      \
    bc1[lane] = o1v;                                                              \
    P1[S1] = b1r + xhalfsum(d1o);                                                 \
    /* layer 2 */                                                                 \
    float n2, d2o;                                                                \
    ldot16x2(bc1 + hoff, w2n, w2o, n2, d2o);                                      \
    float o2v = elur(xhalfsum(n2) + P2[S2]);                                      \
    bc2[lane] = o2v;                                                              \
    P2[S2] = b2r + xhalfsum(d2o);                                                 \
    /* layer 3 */                                                                 \
    float n3, d3o;                                                                \
    ldot16x2(bc2 + hoff, w3n, w3o, n3, d3o);                                      \
    float a3m = elur(xhalfsum(n3) + P3[S3]);                                      \
    P3[S3] = b3r + xhalfsum(d3o);                                                 \
    if (DO_OUT) {                                                                 \
      /* feedback gumbel-softmax: single exp2, no max-sub */                      \
      float F = fexp2(fmaf(a3m, klog, g2_own));                                   \
      float S = F; RED8_SUM(S);                                                   \
      float r2 = frcp(S);                                                         \
      RP = r2;                                                                    \
      float _t = DPP_ROR4(F);                                                     \
      ZP[0] = DPP_QP0(F);  ZP[1] = DPP_QP1(F);  ZP[2] = DPP_QP2(F);               \
      ZP[3] = DPP_QP3(F);                                                         \
      ZP[4] = DPP_QP0(_t); ZP[5] = DPP_QP1(_t); ZP[6] = DPP_QP2(_t);              \
      ZP[7] = DPP_QP3(_t);                                                        \
      /* off-path: old-tap z-dot wzo.y(q_) — consumed at step q_+2 */             \
      {                                                                           \
        float z0 = fmaf(wzo[0], ZP[0], fmaf(wzo[1], ZP[1], 0.f));                 \
        float z1 = fmaf(wzo[2], ZP[2], fmaf(wzo[3], ZP[3], 0.f));                 \
        float z2 = fmaf(wzo[4], ZP[4], fmaf(wzo[5], ZP[5], 0.f));                 \
        float z3 = fmaf(wzo[6], ZP[6], fmaf(wzo[7], ZP[7], 0.f));                 \
        ZQ2n = ((z0 + z1) + (z2 + z3)) * r2;                                      \
      }                                                                           \
      /* off-path: log-softmax output (keeps max for stability) */                \
      float mx = a3m; RED8_MAX(mx);                                               \
      float e = fexp(a3m - mx);                                                   \
      float se = e; RED8_SUM(se);                                                 \
      float lse = mx + flog(se);                                                  \
      if (lane < 8) {                                                             \
        outg[zoff + lane * TLEN + q_ + 1]       = F * r2;                         \
        outg[qoff + lane * NSTEPS + (q_ - 15)]  = a3m - lse;                      \
      }                                                                           \
    }                                                                             \
    /* park x-part + old-z for step q_+1 (xcol data preloaded at step start) */   \
    {                                                                             \
      float s0 = fmaf(wxr[0], _xa.x, fmaf(wxr[1], _xa.y, 0.f));                   \
      float s1 = fmaf(wxr[2], _xa.z, fmaf(wxr[3], _xa.w, 0.f));                   \
      float s2 = fmaf(wxr[4], _xb.x, fmaf(wxr[5], _xb.y, 0.f));                   \
      float s3 = fmaf(wxr[6], _xb.z, fmaf(wxr[7], _xb.w, 0.f));                   \
      float xp = (s0 + s1) + (s2 + s3);                                           \
      XZ = xhalfsum(xp) + b0r + ZQ2;                                              \
      ZQ2 = ZQ2n;                                                                 \
    }                                                                             \
  }

__global__ __launch_bounds__(64, 1)
void regime_scan_kernel(const float* __restrict__ xg,
                        const float* __restrict__ tempg,
                        const float* __restrict__ ug,
                        const float* __restrict__ w0g,
                        const float* __restrict__ b0g,
                        const float* __restrict__ w1g,
                        const float* __restrict__ b1g,
                        const float* __restrict__ w2g,
                        const float* __restrict__ b2g,
                        const float* __restrict__ w3g,
                        const float* __restrict__ b3g,
                        float* __restrict__ outg)
{
    __shared__ __align__(16) float xcol[527][8];     // 16.9 KB
    __shared__ __align__(16) float gls[NSTEPS * NK]; // 15.9 KB (holds g2)
    __shared__ __align__(16) float bc0[64], bc1[64], bc2[64];

    const int lane = threadIdx.x;
    const int b    = blockIdx.x;
    const int c    = lane & 31;            // channel owned
    const int o3   = lane & 7;             // layer-3 channel owned
    const int half = lane >> 5;            // K-half owned (layers 1-3)
    const int hoff = half << 4;            // float offset into bc
    const int tap  = (lane < 32) ? 1 : 0;  // x-park tap role
    const int p4   = (lane & 4);           // slot-order parity*4

    // ---- per-lane weights ----
    float wzn[8], wzo[8];                  // layer0 z weights, slot order
    #pragma unroll
    for (int k = 0; k < 8; ++k) {
        int ch = k ^ p4;
        wzn[k] = w0g[c * 32 + (8 + ch) * 2 + 1];
        wzo[k] = w0g[c * 32 + (8 + ch) * 2 + 0];
    }
    float wxr[8];
    #pragma unroll
    for (int d = 0; d < 8; ++d) wxr[d] = w0g[c * 32 + d * 2 + tap];
    float w1n[16], w1o[16], w2n[16], w2o[16], w3n[16], w3o[16];
    #pragma unroll
    for (int i = 0; i < 16; ++i) {
        int j = hoff + i;
        w1n[i] = w1g[c * 64 + j * 2 + 1];
        w1o[i] = w1g[c * 64 + j * 2 + 0];
        w2n[i] = w2g[c * 64 + j * 2 + 1];
        w2o[i] = w2g[c * 64 + j * 2 + 0];
        w3n[i] = w3g[o3 * 64 + j * 2 + 1];
        w3o[i] = w3g[o3 * 64 + j * 2 + 0];
    }
    const float b0r  = b0g[c];
    const float b1r  = b1g[c];
    const float b2r  = b2g[c];
    const float b3r  = b3g[o3];
    const float tinv = frcp(tempg[0]);
    const float klog = tinv * INVLN2f;     // a3 coefficient in exp2 domain

    // ---- prologue: x columns ----
    if (lane < 15) {
        #pragma unroll
        for (int d = 0; d < ND; ++d) xcol[lane][d] = 0.f;
    }
    const float* xb = xg + b * (ND * TLEN);
    for (int t = lane; t < TLEN; t += 64) {
        #pragma unroll
        for (int d = 0; d < ND; ++d) xcol[15 + t][d] = xb[d * TLEN + t];
    }
    // ---- prologue: Gumbel noise, pre-scaled: g2 = g * tinv / ln2 ----
    for (int idx = lane; idx < NSTEPS * NK; idx += 64) {
        int s = idx >> 3, k = idx & 7;
        float uu = ug[s * (NB * NK) + b * NK + k];
        float g  = -flog(-flog(uu + 1e-10f) + 1e-10f);
        gls[idx] = g * klog;
    }
    // ---- z_all[:, :, 0:16] = 0 ----
    const int zoff = b * (NK * TLEN);
    const int qoff = NB * NK * TLEN + b * (NK * NSTEPS);
    for (int idx = lane; idx < NK * 16; idx += 64) {
        outg[zoff + (idx >> 4) * TLEN + (idx & 15)] = 0.f;
    }

    // ---- state ----
    float zA[8], zB[8];
    #pragma unroll
    for (int k = 0; k < 8; ++k) { zA[k] = 0.f; zB[k] = 0.f; }
    float RA = 1.f, RB = 1.f;              // 1/sum for each z buffer
    float P1[2] = { b1r, b1r };
    float P2[4] = { b2r, b2r, b2r, b2r };
    float P3[8];
    #pragma unroll
    for (int k = 0; k < 8; ++k) P3[k] = b3r;
    float ZQ2 = 0.f, ZQ2n = 0.f;
    float XZ;
    {
        const float4* xq = (const float4*)&xcol[tap][0];
        float4 xa = xq[0], xbv = xq[1];
        float s0 = fmaf(wxr[0], xa.x, fmaf(wxr[1], xa.y, 0.f));
        float s1 = fmaf(wxr[2], xa.z, fmaf(wxr[3], xa.w, 0.f));
        float s2 = fmaf(wxr[4], xbv.x, fmaf(wxr[5], xbv.y, 0.f));
        float s3 = fmaf(wxr[6], xbv.z, fmaf(wxr[7], xbv.w, 0.f));
        XZ = xhalfsum((s0 + s1) + (s2 + s3)) + b0r;   // old-tap z = 0
    }

    // ---- warmup q=1..14 ----
    #pragma unroll
    for (int q = 1; q <= 14; ++q) STEP(q, q & 1, q & 3, q & 7, zA, zB, RA, RB, 0);

    // ---- main loop q=15..510, unrolled by 8; z double-buffer by parity ----
    for (int qb = 15; qb <= 503; qb += 8) {
        #pragma unroll
        for (int u = 0; u < 8; u += 2) {
            STEP(qb + u,     (15 + u) & 1, (15 + u) & 3, (15 + u) & 7, zA, zB, RA, RB, 1);
            STEP(qb + u + 1, (16 + u) & 1, (16 + u) & 3, (16 + u) & 7, zB, zA, RB, RA, 1);
        }
    }
}

extern "C" void kernel_launch(void* const* d_in, const int* in_sizes, int n_in,
                              void* d_out, int out_size, void* d_ws, size_t ws_size,
                              hipStream_t stream) {
    (void)in_sizes; (void)n_in; (void)out_size; (void)d_ws; (void)ws_size;
    regime_scan_kernel<<<dim3(NB), dim3(64), 0, stream>>>(
        (const float*)d_in[0],   // x
        (const float*)d_in[1],   // temp
        (const float*)d_in[2],   // u
        (const float*)d_in[3],   // w0
        (const float*)d_in[4],   // b0
        (const float*)d_in[5],   // w1
        (const float*)d_in[6],   // b1
        (const float*)d_in[7],   // w2
        (const float*)d_in[8],   // b2
        (const float*)d_in[9],   // w3
        (const float*)d_in[10],  // b3
        (float*)d_out);
}